// Round 6
// baseline (311.198 us; speedup 1.0000x reference)
//
#include <hip/hip_runtime.h>

using f16   = _Float16;
using f16x4 = __attribute__((ext_vector_type(4))) _Float16;
using f16x8 = __attribute__((ext_vector_type(8))) _Float16;
using f32x4 = __attribute__((ext_vector_type(4))) float;
using u32x4 = __attribute__((ext_vector_type(4))) unsigned int;
using fp16x2_raw = __fp16 __attribute__((ext_vector_type(2)));

#define MFMA16(a, b, c) __builtin_amdgcn_mfma_f32_16x16x32_f16((a), (b), (c), 0, 0, 0)

namespace {
constexpr int kT = 8, kWd = 14, kS = 196;
constexpr int kN = 1568;      // T*S (sequence length per batch)
constexpr int kM = 3136;      // B*N (GEMM rows)
constexpr int kHeads = 12;
constexpr int kNp = 1664;     // padded N (13*128)
// workspace byte offsets (all 256-aligned)
constexpr size_t OFF_Q    = 0;            // qf   [24][Np][64] f16 (unscaled q)
constexpr size_t OFF_QE   = 5111808;      // qe   [24][Np][32] f16 (relH/relW dots + mask slot)
constexpr size_t OFF_QET  = 7667712;      // qet  [24][Np][8]  f32 (relT dots)
constexpr size_t OFF_K    = 8945664;      // kf   [24][Np][64] f16 (k*0.125); dead after kswz
constexpr size_t OFF_O    = OFF_K;        // Of   [3200][768] f16 ALIASES kf (attn runs after kswz)
constexpr size_t OFF_KONE = 14057472;     // kone [Np][32] f16 (one-hot h/w + validity)
constexpr size_t OFF_KSWZ = 14163968;     // kswz [24][13][8][3][64][8] f16 (K_ext B-frags)
constexpr size_t OFF_VSWZ = 21831680;     // vswz [24][13][4][4][64][8] f16 (V B-frags)
constexpr size_t WS_TOTAL = 26943488;

__device__ inline f16x4 pack4(float4 v) {
  union { fp16x2_raw h2[2]; f16x4 f4; } u;
  u.h2[0] = __builtin_amdgcn_cvt_pkrtz(v.x, v.y);
  u.h2[1] = __builtin_amdgcn_cvt_pkrtz(v.z, v.w);
  return u.f4;
}
}

// ---------------- QKV GEMM: C[3136,2304] = X[3136,768] @ W[2304,768]^T ----------
// q (unscaled), k*scale stored direct; v stored DIRECTLY in vswz fragment order
// via the sE transpose. sE aliases sA/sB (epilogue-only use) -> 34816 B LDS.
__global__ __launch_bounds__(256) void arp_gemm_qkv(
    const float* __restrict__ X, const float* __restrict__ W,
    f16* __restrict__ qf, f16* __restrict__ kf, f16* __restrict__ vswz) {
  __shared__ char smem[128 * 136 * 2];          // pool: sA+sB (loop) / sE (epilogue)
  f16* sA = (f16*)smem;                          // 128*40*2 = 10240 B
  f16* sB = (f16*)(smem + 10240);                // 128*40*2 = 10240 B
  f16* sE = (f16*)smem;                          // 128*136*2 = 34816 B
  const int tid = threadIdx.x, lane = tid & 63, wv = tid >> 6;
  const int m0 = blockIdx.y * 128, n0 = blockIdx.x * 128;
  const int wm = (wv & 1) * 64, wn = (wv >> 1) * 64;
  const int frow = lane & 15, quad = lane >> 4, fcol = quad * 8;
  const f32x4 vzero = {0.f, 0.f, 0.f, 0.f};
  f32x4 acc[4][4];
  for (int i = 0; i < 4; ++i)
    for (int j = 0; j < 4; ++j) acc[i][j] = vzero;

  for (int kt = 0; kt < 24; ++kt) {  // K=768, BK=32
#pragma unroll
    for (int i = 0; i < 4; ++i) {
      int idx = i * 256 + tid;
      int r = idx >> 3, c4 = (idx & 7) * 4;
      float4 v = {0.f, 0.f, 0.f, 0.f};
      int gm = m0 + r;
      if (gm < kM) v = *(const float4*)(X + (size_t)gm * 768 + kt * 32 + c4);
      *(f16x4*)&sA[r * 40 + c4] = pack4(v);
    }
#pragma unroll
    for (int i = 0; i < 4; ++i) {
      int idx = i * 256 + tid;
      int r = idx >> 3, c4 = (idx & 7) * 4;
      float4 v = *(const float4*)(W + (size_t)(n0 + r) * 768 + kt * 32 + c4);
      *(f16x4*)&sB[r * 40 + c4] = pack4(v);
    }
    __syncthreads();
    f16x8 af[4], bf[4];
#pragma unroll
    for (int t = 0; t < 4; ++t) {
      af[t] = *(const f16x8*)&sA[(wm + t * 16 + frow) * 40 + fcol];
      bf[t] = *(const f16x8*)&sB[(wn + t * 16 + frow) * 40 + fcol];
    }
#pragma unroll
    for (int mt = 0; mt < 4; ++mt)
#pragma unroll
      for (int nt = 0; nt < 4; ++nt)
        acc[mt][nt] = MFMA16(af[mt], bf[nt], acc[mt][nt]);
    __syncthreads();   // also separates last sA/sB reads from sE writes below
  }

  if (n0 >= 1536) {
    // ---- v-block: transpose through sE, store straight into vswz fragments ----
#pragma unroll
    for (int mt = 0; mt < 4; ++mt)
#pragma unroll
      for (int nt = 0; nt < 4; ++nt) {
        int cl = wn + nt * 16 + frow;             // col_local 0..127
#pragma unroll
        for (int rg = 0; rg < 4; ++rg) {
          int rl = wm + mt * 16 + quad * 4 + rg;  // row_local 0..127
          sE[cl * 136 + rl] = (f16)acc[mt][nt][rg];
        }
      }
    __syncthreads();
    int cl = tid >> 1;                 // 0..127
    int rb = (tid & 1) * 64;           // row-block 0/64
    int rem = n0 + cl - 1536;          // 0..767
    int hh = rem >> 6, d = rem & 63;
    int td = d >> 4, fr = d & 15;
#pragma unroll
    for (int j = 0; j < 8; ++j) {
      int ms = m0 + rb + j * 8;        // 8 consecutive keys, 8-aligned
      if (ms < kM) {
        int bb = (ms >= kN) ? 1 : 0;
        int ns = ms - bb * kN;         // mult of 8 (kN%8==0)
        int bh = bb * kHeads + hh;
        int kt2 = ns >> 7, kr = ns & 127;
        int kc = kr >> 5, qd = (kr >> 3) & 3;
        f16* dst = vswz + ((((size_t)(bh * 13 + kt2)) * 4 + td) * 4 + kc) * 512
                        + (qd * 16 + fr) * 8;
        *(u32x4*)dst = *(const u32x4*)&sE[cl * 136 + rb + j * 8];
      }
    }
  } else {
    // ---- q/k block: direct stores ----
#pragma unroll
    for (int mt = 0; mt < 4; ++mt) {
      int rbase = m0 + wm + mt * 16 + quad * 4;
#pragma unroll
      for (int nt = 0; nt < 4; ++nt) {
        int col0 = n0 + wn + nt * 16;
        int which = col0 / 768;
        int rem = col0 - which * 768;
        int hh = rem >> 6;
        int d = (rem & 63) + frow;
#pragma unroll
        for (int rg = 0; rg < 4; ++rg) {
          int m = rbase + rg;
          if (m < kM) {
            int bb = (m >= kN) ? 1 : 0;
            int ns = m - bb * kN;
            int bh = bb * kHeads + hh;
            float av = acc[mt][nt][rg];
            if (which == 1) av *= 0.125f;
            f16 hv = (f16)av;
            if (which == 0) qf[((size_t)bh * kNp + ns) * 64 + d] = hv;
            else            kf[((size_t)bh * kNp + ns) * 64 + d] = hv;
          }
        }
      }
    }
  }
}

// ---------------- K one-hot extension (bh-independent): kone[n][32] -------------
// 0..13 = onehot(h2), 14..27 = onehot(w2), 28 = 1 if padded key, 29..31 = 0
__global__ __launch_bounds__(256) void arp_kone(f16* __restrict__ kone) {
  int tid = blockIdx.x * 256 + threadIdx.x;
  if (tid >= kNp * 32) return;
  int n = tid >> 5, c = tid & 31;
  int t2 = n / kS; int rm = n - t2 * kS;
  int h2 = rm / kWd; int w2 = rm - h2 * kWd;
  float v = 0.f;
  if (c == h2) v = 1.f;
  else if (c == 14 + w2) v = 1.f;
  else if (c == 28 && n >= kN) v = 1.f;
  kone[tid] = (f16)v;
}

// ---------------- Q extension: relH/relW dots -> qe (f16), relT dots -> qet (f32)
__global__ __launch_bounds__(256) void arp_qext(
    const f16* __restrict__ qf,
    const float* __restrict__ Rh, const float* __restrict__ Rw, const float* __restrict__ Rt,
    f16* __restrict__ qe, float* __restrict__ qet) {
  int tid = blockIdx.x * 256 + threadIdx.x;
  const int TOT = 24 * kN * 36;
  if (tid >= TOT) return;
  int e = tid % 36;
  int rem = tid / 36;
  int q = rem % kN;
  int bh = rem / kN;
  int tq = q / kS, sr = q - tq * kS;
  int hq = sr / kWd, wq = sr - hq * kWd;
  const float* R;
  int t2 = 0; bool isT = false;
  if (e < 14)      R = Rh + (hq - e + 13) * 64;
  else if (e < 28) R = Rw + (wq - (e - 14) + 13) * 64;
  else { isT = true; t2 = e - 28; R = Rt + (tq - t2 + 7) * 64; }
  const f16x8* qv = (const f16x8*)(qf + ((size_t)bh * kNp + q) * 64);
  const float4* R4 = (const float4*)R;
  float sum = 0.f;
#pragma unroll
  for (int i = 0; i < 8; ++i) {
    f16x8 qh = qv[i];
    float4 a = R4[i * 2], b = R4[i * 2 + 1];
    sum += (float)qh[0] * a.x + (float)qh[1] * a.y + (float)qh[2] * a.z + (float)qh[3] * a.w
         + (float)qh[4] * b.x + (float)qh[5] * b.y + (float)qh[6] * b.z + (float)qh[7] * b.w;
  }
  if (isT) qet[((size_t)bh * kNp + q) * 8 + t2] = sum;
  else     qe[((size_t)bh * kNp + q) * 32 + e] = (f16)sum;
  if (e == 0) {
    f16* o = qe + ((size_t)bh * kNp + q) * 32;
    o[28] = (f16)(-10000.f); o[29] = (f16)0.f; o[30] = (f16)0.f; o[31] = (f16)0.f;
  }
}

// ---------------- K_ext -> B-fragment swizzle: kswz[bh][13][nt8][s3][lane64][8] --
// frag elem (lane,j): key = kt*128 + nt*16 + (lane&15); dim = s*32 + (lane>>4)*8 + j
__global__ __launch_bounds__(256) void arp_kswz(
    const f16* __restrict__ kf, const f16* __restrict__ kone, f16* __restrict__ kswz) {
  int gid = blockIdx.x * 256 + threadIdx.x;
  const int TOT = 24 * 13 * 8 * 3 * 64;
  if (gid >= TOT) return;
  int lane = gid & 63;
  int r = gid >> 6;
  int s = r % 3; r /= 3;
  int nt = r & 7; r >>= 3;
  int kt = r % 13;
  int bh = r / 13;
  int frow = lane & 15, quad = lane >> 4;
  int key = kt * 128 + nt * 16 + frow;
  int dim = s * 32 + quad * 8;
  u32x4 v;
  if (dim < 64) v = *(const u32x4*)(kf + ((size_t)bh * kNp + key) * 64 + dim);
  else          v = *(const u32x4*)(kone + (size_t)key * 32 + (dim - 64));
  *(u32x4*)(kswz + (size_t)gid * 8) = v;
}

// ---------------- flash attention: barrier-free, B-frags from swizzled global ----
// grid (25 q-tiles of 64, 24 bh); 4 waves x 16 q-rows; K_ext = 96 dims (3 steps).
// No __syncthreads: sP and sQT are per-wave (intra-wave lgkmcnt ordering only).
__global__ __launch_bounds__(256, 3) void arp_attn(
    const f16* __restrict__ qf, const f16* __restrict__ qe, const float* __restrict__ qet,
    const f16* __restrict__ kswz, const f16* __restrict__ vswz, f16* __restrict__ Of) {
  __shared__ f16 sP[4][16 * 136];     // per-wave P round-trip
  __shared__ float sQT[4][16 * 8];    // per-wave rel_t table

  const int tid = threadIdx.x, lane = tid & 63, wv = tid >> 6;
  const int q0 = blockIdx.x * 64;
  const int bh = blockIdx.y;
  const int b = bh / kHeads, hh = bh - b * kHeads;
  const int frow = lane & 15, quad = lane >> 4;
  const f32x4 vzero = {0.f, 0.f, 0.f, 0.f};

  {  // per-wave rel_t staging: 16 rows x 8 f32, 2 f32/lane
    int row = lane >> 2, c2 = (lane & 3) * 2;
    *(float2*)&sQT[wv][row * 8 + c2] =
        *(const float2*)(qet + ((size_t)bh * kNp + q0 + wv * 16 + row) * 8 + c2);
  }
  // persistent Q fragments (A-layout), rows q0 + wv*16 + frow
  f16x8 aQ0, aQ1, aQE;
  {
    int row = q0 + wv * 16 + frow;
    const f16* qp = qf + ((size_t)bh * kNp + row) * 64;
    aQ0 = *(const f16x8*)(qp + quad * 8);
    aQ1 = *(const f16x8*)(qp + 32 + quad * 8);
    aQE = *(const f16x8*)(qe + ((size_t)bh * kNp + row) * 32 + quad * 8);
  }
  float m_i[4], l_i[4], alpha[4];
  f32x4 Oc[4];
#pragma unroll
  for (int r = 0; r < 4; ++r) { m_i[r] = -__builtin_inff(); l_i[r] = 0.f; Oc[r] = vzero; }

  const f16* kb = kswz + (size_t)bh * 13 * 12288;
  const f16* vb = vswz + (size_t)bh * 13 * 8192;
  f16* sPw = sP[wv];

  for (int kt = 0; kt < 13; ++kt) {
    const f16* kp = kb + (size_t)kt * 12288 + lane * 8;
    // QK^T + h/w bias + mask: 96 dims = 3 MFMA steps per key-group
    f32x4 Sc[8];
#pragma unroll
    for (int nt = 0; nt < 8; ++nt) {
      f16x8 k0 = *(const f16x8*)(kp + (nt * 3 + 0) * 512);
      f16x8 k1 = *(const f16x8*)(kp + (nt * 3 + 1) * 512);
      f16x8 k2 = *(const f16x8*)(kp + (nt * 3 + 2) * 512);
      f32x4 s = MFMA16(aQ0, k0, vzero);
      s = MFMA16(aQ1, k1, s);
      Sc[nt] = MFMA16(aQE, k2, s);
    }
    // rel_t add (<=2 distinct t2 per 128-key tile)
    const int base = kt * 128;
    const int t2lo = base / kS;
    int t2hi = (base + 127) / kS; if (t2hi > kT - 1) t2hi = kT - 1;
    const int jb = (t2lo + 1) * kS;
    float vlo[4], vhi[4];
#pragma unroll
    for (int r = 0; r < 4; ++r) {
      vlo[r] = sQT[wv][(quad * 4 + r) * 8 + t2lo];
      vhi[r] = sQT[wv][(quad * 4 + r) * 8 + t2hi];
    }
#pragma unroll
    for (int nt = 0; nt < 8; ++nt) {
      int jg = base + nt * 16 + frow;
      bool lo = jg < jb;
#pragma unroll
      for (int r = 0; r < 4; ++r) Sc[nt][r] += lo ? vlo[r] : vhi[r];
    }
    // online softmax per row
#pragma unroll
    for (int r = 0; r < 4; ++r) {
      float mx = Sc[0][r];
#pragma unroll
      for (int nt = 1; nt < 8; ++nt) mx = fmaxf(mx, Sc[nt][r]);
#pragma unroll
      for (int off = 1; off < 16; off <<= 1) mx = fmaxf(mx, __shfl_xor(mx, off, 64));
      float mn = fmaxf(m_i[r], mx);
      alpha[r] = __expf(m_i[r] - mn);
      m_i[r] = mn;
      float rs = 0.f;
#pragma unroll
      for (int nt = 0; nt < 8; ++nt) {
        float p = __expf(Sc[nt][r] - mn);
        Sc[nt][r] = p;
        rs += p;
      }
#pragma unroll
      for (int off = 1; off < 16; off <<= 1) rs += __shfl_xor(rs, off, 64);
      l_i[r] = l_i[r] * alpha[r] + rs;
    }
#pragma unroll
    for (int td = 0; td < 4; ++td) {
      Oc[td][0] *= alpha[0]; Oc[td][1] *= alpha[1];
      Oc[td][2] *= alpha[2]; Oc[td][3] *= alpha[3];
    }
    // V fragments (independent of the LDS round-trip below; overlaps it)
    const f16* vp = vb + (size_t)kt * 8192 + lane * 8;
    f16x8 bV[4][4];
#pragma unroll
    for (int td = 0; td < 4; ++td)
#pragma unroll
      for (int kc = 0; kc < 4; ++kc)
        bV[td][kc] = *(const f16x8*)(vp + (td * 4 + kc) * 512);
    // P: C-layout -> per-wave LDS -> A-layout
#pragma unroll
    for (int nt = 0; nt < 8; ++nt)
#pragma unroll
      for (int r = 0; r < 4; ++r)
        sPw[(quad * 4 + r) * 136 + nt * 16 + frow] = (f16)Sc[nt][r];
    // PV: O[16 x 64] += P[16 x 128] @ V[128 x 64]
#pragma unroll
    for (int kc = 0; kc < 4; ++kc) {
      f16x8 aP = *(const f16x8*)&sPw[frow * 136 + kc * 32 + quad * 8];
#pragma unroll
      for (int td = 0; td < 4; ++td)
        Oc[td] = MFMA16(aP, bV[td][kc], Oc[td]);
    }
  }
  // epilogue
#pragma unroll
  for (int td = 0; td < 4; ++td)
#pragma unroll
    for (int r = 0; r < 4; ++r) {
      int row = q0 + wv * 16 + quad * 4 + r;
      if (row < kN) {
        float val = Oc[td][r] / l_i[r];
        Of[((size_t)(b * kN + row)) * 768 + hh * 64 + td * 16 + frow] = (f16)val;
      }
    }
}

// ---------------- proj GEMM: out[3136,768] = O[3136,768] @ Wp[768,768]^T + bias --
__global__ __launch_bounds__(256) void arp_gemm_proj(
    const f16* __restrict__ A, const float* __restrict__ W,
    const float* __restrict__ bias, float* __restrict__ out) {
  __shared__ f16 sA[128 * 40];
  __shared__ f16 sB[128 * 40];
  const int tid = threadIdx.x, lane = tid & 63, wv = tid >> 6;
  const int m0 = blockIdx.y * 128, n0 = blockIdx.x * 128;
  const int wm = (wv & 1) * 64, wn = (wv >> 1) * 64;
  const int frow = lane & 15, fcol = (lane >> 4) * 8;
  const f32x4 vzero = {0.f, 0.f, 0.f, 0.f};
  f32x4 acc[4][4];
  for (int i = 0; i < 4; ++i)
    for (int j = 0; j < 4; ++j) acc[i][j] = vzero;

  for (int kt = 0; kt < 24; ++kt) {
#pragma unroll
    for (int i = 0; i < 2; ++i) {
      int idx = i * 256 + tid;
      int r = idx >> 2, c8 = (idx & 3) * 8;
      u32x4 v = *(const u32x4*)(A + (size_t)(m0 + r) * 768 + kt * 32 + c8);
      *(u32x4*)&sA[r * 40 + c8] = v;
    }
#pragma unroll
    for (int i = 0; i < 4; ++i) {
      int idx = i * 256 + tid;
      int r = idx >> 3, c4 = (idx & 7) * 4;
      float4 v = *(const float4*)(W + (size_t)(n0 + r) * 768 + kt * 32 + c4);
      *(f16x4*)&sB[r * 40 + c4] = pack4(v);
    }
    __syncthreads();
    f16x8 af[4], bf[4];
#pragma unroll
    for (int t = 0; t < 4; ++t) {
      af[t] = *(const f16x8*)&sA[(wm + t * 16 + frow) * 40 + fcol];
      bf[t] = *(const f16x8*)&sB[(wn + t * 16 + frow) * 40 + fcol];
    }
#pragma unroll
    for (int mt = 0; mt < 4; ++mt)
#pragma unroll
      for (int nt = 0; nt < 4; ++nt)
        acc[mt][nt] = MFMA16(af[mt], bf[nt], acc[mt][nt]);
    __syncthreads();
  }
#pragma unroll
  for (int mt = 0; mt < 4; ++mt) {
    int rbase = m0 + wm + mt * 16 + (lane >> 4) * 4;
#pragma unroll
    for (int nt = 0; nt < 4; ++nt) {
      int col = n0 + wn + nt * 16 + frow;
      float bv = bias[col];
#pragma unroll
      for (int rg = 0; rg < 4; ++rg) {
        int m = rbase + rg;
        if (m < kM) out[(size_t)m * 768 + col] = acc[mt][nt][rg] + bv;
      }
    }
  }
}

extern "C" void kernel_launch(void* const* d_in, const int* in_sizes, int n_in,
                              void* d_out, int out_size, void* d_ws, size_t ws_size,
                              hipStream_t stream) {
  if (ws_size < WS_TOTAL) return;
  const float* x      = (const float*)d_in[0];
  const float* qkv_w  = (const float*)d_in[1];
  const float* proj_w = (const float*)d_in[2];
  const float* proj_b = (const float*)d_in[3];
  const float* rph    = (const float*)d_in[4];
  const float* rpw    = (const float*)d_in[5];
  const float* rpt    = (const float*)d_in[6];
  char* ws = (char*)d_ws;
  f16*   qf   = (f16*)(ws + OFF_Q);
  f16*   qe   = (f16*)(ws + OFF_QE);
  float* qet  = (float*)(ws + OFF_QET);
  f16*   kf   = (f16*)(ws + OFF_K);
  f16*   kone = (f16*)(ws + OFF_KONE);
  f16*   kswz = (f16*)(ws + OFF_KSWZ);
  f16*   vswz = (f16*)(ws + OFF_VSWZ);
  f16*   Of   = (f16*)(ws + OFF_O);       // aliases kf (kf dead after arp_kswz)

  arp_kone<<<(kNp * 32 + 255) / 256, 256, 0, stream>>>(kone);
  arp_gemm_qkv<<<dim3(18, 25), 256, 0, stream>>>(x, qkv_w, qf, kf, vswz);
  int qeTot = 24 * kN * 36;
  arp_qext<<<(qeTot + 255) / 256, 256, 0, stream>>>(qf, rph, rpw, rpt, qe, qet);
  int kswzTot = 24 * 13 * 8 * 3 * 64;
  arp_kswz<<<(kswzTot + 255) / 256, 256, 0, stream>>>(kf, kone, kswz);
  arp_attn<<<dim3(25, 24), 256, 0, stream>>>(qf, qe, qet, kswz, vswz, Of);
  arp_gemm_proj<<<dim3(6, 25), 256, 0, stream>>>(Of, proj_w, proj_b, (float*)d_out);
}

// Round 7
// 255.120 us; speedup vs baseline: 1.2198x; 1.2198x over previous
//
#include <hip/hip_runtime.h>

using f16   = _Float16;
using f16x4 = __attribute__((ext_vector_type(4))) _Float16;
using f16x8 = __attribute__((ext_vector_type(8))) _Float16;
using f32x4 = __attribute__((ext_vector_type(4))) float;
using u32x4 = __attribute__((ext_vector_type(4))) unsigned int;
using fp16x2_raw = __fp16 __attribute__((ext_vector_type(2)));

#define MFMA16(a, b, c) __builtin_amdgcn_mfma_f32_16x16x32_f16((a), (b), (c), 0, 0, 0)

namespace {
constexpr int kT = 8, kWd = 14, kS = 196;
constexpr int kN = 1568;      // T*S (sequence length per batch)
constexpr int kM = 3136;      // B*N (GEMM rows)
constexpr int kHeads = 12;
constexpr int kNp = 1664;     // padded N (13*128)
constexpr float kLog2e = 1.4426950408889634f;
// workspace byte offsets (all 256-aligned)
constexpr size_t OFF_Q    = 0;            // qf    [24][Np][64] f16 (q * log2e)
constexpr size_t OFF_QE   = 5111808;      // qe    [24][Np][64] f16 (rel dots * log2e; [36]=-30000)
constexpr size_t OFF_KF   = 10223616;     // kfrag [24][13][8][2][64][8] f16 (K B-frags, dims 0..63)
constexpr size_t OFF_KONE = 15335424;     // konefrag [13][8][2][64][8] f16 (one-hot ext dims 64..127)
constexpr size_t OFF_VSWZ = 15548416;     // vswz  [24][13][4][4][64][8] f16 (V B-frags)
constexpr size_t OFF_O    = 20660224;     // Of    [3200][768] f16
constexpr size_t WS_TOTAL = 25575424;

__device__ inline f16x4 pack4(float4 v) {
  union { fp16x2_raw h2[2]; f16x4 f4; } u;
  u.h2[0] = __builtin_amdgcn_cvt_pkrtz(v.x, v.y);
  u.h2[1] = __builtin_amdgcn_cvt_pkrtz(v.z, v.w);
  return u.f4;
}

__device__ inline float fast_exp2(float x) {
#if __has_builtin(__builtin_amdgcn_exp2f)
  return __builtin_amdgcn_exp2f(x);
#else
  return __expf(x * 0.6931471805599453f);
#endif
}
}

// ---------------- QKV GEMM: C[3136,2304] = X[3136,768] @ W[2304,768]^T ----------
// q stored *log2e (direct); k stored *0.125 in FRAGMENT order (kfrag);
// v stored in FRAGMENT order (vswz) via the sE transpose.
__global__ __launch_bounds__(256) void arp_gemm_qkv(
    const float* __restrict__ X, const float* __restrict__ W,
    f16* __restrict__ qf, f16* __restrict__ kfrag, f16* __restrict__ vswz) {
  __shared__ char smem[128 * 136 * 2];          // pool: sA+sB (loop) / sE (epilogue)
  f16* sA = (f16*)smem;                          // 128*40*2 = 10240 B
  f16* sB = (f16*)(smem + 10240);                // 128*40*2 = 10240 B
  f16* sE = (f16*)smem;                          // 128*136*2 = 34816 B
  const int tid = threadIdx.x, lane = tid & 63, wv = tid >> 6;
  const int m0 = blockIdx.y * 128, n0 = blockIdx.x * 128;
  const int wm = (wv & 1) * 64, wn = (wv >> 1) * 64;
  const int frow = lane & 15, quad = lane >> 4, fcol = quad * 8;
  const f32x4 vzero = {0.f, 0.f, 0.f, 0.f};
  f32x4 acc[4][4];
  for (int i = 0; i < 4; ++i)
    for (int j = 0; j < 4; ++j) acc[i][j] = vzero;

  for (int kt = 0; kt < 24; ++kt) {  // K=768, BK=32
#pragma unroll
    for (int i = 0; i < 4; ++i) {
      int idx = i * 256 + tid;
      int r = idx >> 3, c4 = (idx & 7) * 4;
      float4 v = {0.f, 0.f, 0.f, 0.f};
      int gm = m0 + r;
      if (gm < kM) v = *(const float4*)(X + (size_t)gm * 768 + kt * 32 + c4);
      *(f16x4*)&sA[r * 40 + c4] = pack4(v);
    }
#pragma unroll
    for (int i = 0; i < 4; ++i) {
      int idx = i * 256 + tid;
      int r = idx >> 3, c4 = (idx & 7) * 4;
      float4 v = *(const float4*)(W + (size_t)(n0 + r) * 768 + kt * 32 + c4);
      *(f16x4*)&sB[r * 40 + c4] = pack4(v);
    }
    __syncthreads();
    f16x8 af[4], bf[4];
#pragma unroll
    for (int t = 0; t < 4; ++t) {
      af[t] = *(const f16x8*)&sA[(wm + t * 16 + frow) * 40 + fcol];
      bf[t] = *(const f16x8*)&sB[(wn + t * 16 + frow) * 40 + fcol];
    }
#pragma unroll
    for (int mt = 0; mt < 4; ++mt)
#pragma unroll
      for (int nt = 0; nt < 4; ++nt)
        acc[mt][nt] = MFMA16(af[mt], bf[nt], acc[mt][nt]);
    __syncthreads();   // also separates last sA/sB reads from sE writes below
  }

  if (n0 >= 1536) {
    // ---- v-block: transpose through sE, store straight into vswz fragments ----
#pragma unroll
    for (int mt = 0; mt < 4; ++mt)
#pragma unroll
      for (int nt = 0; nt < 4; ++nt) {
        int cl = wn + nt * 16 + frow;             // col_local 0..127
#pragma unroll
        for (int rg = 0; rg < 4; ++rg) {
          int rl = wm + mt * 16 + quad * 4 + rg;  // row_local 0..127
          sE[cl * 136 + rl] = (f16)acc[mt][nt][rg];
        }
      }
    __syncthreads();
    int cl = tid >> 1;                 // 0..127
    int rb = (tid & 1) * 64;           // row-block 0/64
    int rem = n0 + cl - 1536;          // 0..767
    int hh = rem >> 6, d = rem & 63;
    int td = d >> 4, fr = d & 15;
#pragma unroll
    for (int j = 0; j < 8; ++j) {
      int ms = m0 + rb + j * 8;        // 8 consecutive keys, 8-aligned
      if (ms < kM) {
        int bb = (ms >= kN) ? 1 : 0;
        int ns = ms - bb * kN;         // mult of 8 (kN%8==0)
        int bh = bb * kHeads + hh;
        int kt2 = ns >> 7, kr = ns & 127;
        int kc = kr >> 5, qd = (kr >> 3) & 3;
        f16* dst = vswz + ((((size_t)(bh * 13 + kt2)) * 4 + td) * 4 + kc) * 512
                        + (qd * 16 + fr) * 8;
        *(u32x4*)dst = *(const u32x4*)&sE[cl * 136 + rb + j * 8];
      }
    }
  } else {
    // ---- q/k block: q direct (pre-scaled log2e), k into kfrag fragment order ----
#pragma unroll
    for (int mt = 0; mt < 4; ++mt) {
      int rbase = m0 + wm + mt * 16 + quad * 4;
#pragma unroll
      for (int nt = 0; nt < 4; ++nt) {
        int col0 = n0 + wn + nt * 16;
        int which = col0 / 768;
        int rem = col0 - which * 768;
        int hh = rem >> 6;
        int d = (rem & 63) + frow;
        int s = d >> 5, qd2 = (d >> 3) & 3, j = d & 7;
#pragma unroll
        for (int rg = 0; rg < 4; ++rg) {
          int m = rbase + rg;
          if (m < kM) {
            int bb = (m >= kN) ? 1 : 0;
            int ns = m - bb * kN;
            int bh = bb * kHeads + hh;
            float av = acc[mt][nt][rg];
            if (which == 0) {
              av *= kLog2e;              // log2-domain softmax prescale
              qf[((size_t)bh * kNp + ns) * 64 + d] = (f16)av;
            } else {
              av *= 0.125f;              // softmax scale folded into K
              int kt2 = ns >> 7, nt2 = (ns >> 4) & 7, fr = ns & 15;
              kfrag[(((size_t)(bh * 13 + kt2) * 8 + nt2) * 2 + s) * 512
                    + (qd2 * 16 + fr) * 8 + j] = (f16)av;
            }
          }
        }
      }
    }
  }
}

// ---------------- one-hot ext fragments (bh-independent) ------------------------
// konefrag[kt][nt][s2][lane][j]: ext dim c = s2*32 + (lane>>4)*8 + j for key
// kt*128 + nt*16 + (lane&15). c: 0..13 onehot(h2), 14..27 onehot(w2),
// 28..35 onehot(t2 clamped), 36 = padded-key flag, rest 0.
__global__ __launch_bounds__(256) void arp_konefrag(f16* __restrict__ konefrag) {
  int gid = blockIdx.x * 256 + threadIdx.x;
  const int TOT = 13 * 8 * 2 * 64 * 8;
  if (gid >= TOT) return;
  int j = gid & 7;
  int lane = (gid >> 3) & 63;
  int s2 = (gid >> 9) & 1;
  int nt = (gid >> 10) & 7;
  int kt = gid >> 13;
  int fr = lane & 15, qd = lane >> 4;
  int key = kt * 128 + nt * 16 + fr;
  int c = s2 * 32 + qd * 8 + j;
  int t2 = key / kS; int rm = key - t2 * kS;
  int h2 = rm / kWd; int w2 = rm - h2 * kWd;
  if (t2 > kT - 1) t2 = kT - 1;
  float v = 0.f;
  if (c == h2) v = 1.f;
  else if (c == 14 + w2) v = 1.f;
  else if (c == 28 + t2) v = 1.f;
  else if (c == 36 && key >= kN) v = 1.f;
  konefrag[gid] = (f16)v;
}

// ---------------- Q extension: qe[bh][q][e] = (log2e-scaled) rel dots -----------
// e: 0..13 relH, 14..27 relW, 28..35 relT, 36 = -30000 mask const.
// (qf already carries log2e, so the dots come out pre-scaled.)
__global__ __launch_bounds__(256) void arp_qext(
    const f16* __restrict__ qf,
    const float* __restrict__ Rh, const float* __restrict__ Rw, const float* __restrict__ Rt,
    f16* __restrict__ qe) {
  int tid = blockIdx.x * 256 + threadIdx.x;
  const int TOT = 24 * kN * 37;
  if (tid >= TOT) return;
  int e = tid % 37;
  int rem = tid / 37;
  int q = rem % kN;
  int bh = rem / kN;
  f16* out = qe + ((size_t)bh * kNp + q) * 64;
  if (e == 36) { out[36] = (f16)(-30000.f); return; }
  int tq = q / kS, sr = q - tq * kS;
  int hq = sr / kWd, wq = sr - hq * kWd;
  const float* R;
  if (e < 14)      R = Rh + (hq - e + 13) * 64;
  else if (e < 28) R = Rw + (wq - (e - 14) + 13) * 64;
  else             R = Rt + (tq - (e - 28) + 7) * 64;
  const f16x8* qv = (const f16x8*)(qf + ((size_t)bh * kNp + q) * 64);
  const float4* R4 = (const float4*)R;
  float sum = 0.f;
#pragma unroll
  for (int i = 0; i < 8; ++i) {
    f16x8 qh = qv[i];
    float4 a = R4[i * 2], b = R4[i * 2 + 1];
    sum += (float)qh[0] * a.x + (float)qh[1] * a.y + (float)qh[2] * a.z + (float)qh[3] * a.w
         + (float)qh[4] * b.x + (float)qh[5] * b.y + (float)qh[6] * b.z + (float)qh[7] * b.w;
  }
  out[e] = (f16)sum;
}

// ---------------- flash attention: static-max log2-domain softmax ---------------
// grid (25 q-tiles of 64, 24 bh); 4 waves x 16 q-rows; K_ext = 128 dims (4 steps).
// No online max / no rescale (logits statically bounded); P = exp2(Sc) raw.
// Row-sum l folded into PV via a ones-column B-frag (Oc[4]); zero cross-lane ops
// in the loop. LDS: sKa/sKb (frag-order K) + sV (frag-order V) = 48 KB;
// sP aliases sKa/sKb after barrier C. 3 blocks/CU cap.
__global__ __launch_bounds__(256, 3) void arp_attn(
    const f16* __restrict__ qf, const f16* __restrict__ qe,
    const f16* __restrict__ kfrag, const f16* __restrict__ konefrag,
    const f16* __restrict__ vswz, f16* __restrict__ Of) {
  __shared__ char pool[49152];
  f16* sKa = (f16*)pool;             // 16384 B: K dims 0..63  [nt][s01][64][8]
  f16* sKb = (f16*)(pool + 16384);   // 16384 B: ext dims 64..127
  f16* sV  = (f16*)(pool + 32768);   // 16384 B: V frags [td][kc][64][8]

  const int tid = threadIdx.x, lane = tid & 63, wv = tid >> 6;
  const int q0 = blockIdx.x * 64;
  const int bh = blockIdx.y;
  const int b = bh / kHeads, hh = bh - b * kHeads;
  const int frow = lane & 15, quad = lane >> 4;
  const f32x4 vzero = {0.f, 0.f, 0.f, 0.f};

  // persistent Q_ext fragments (A-layout), rows q0 + wv*16 + frow
  f16x8 aQ0, aQ1, aQE0, aQE1;
  {
    int row = q0 + wv * 16 + frow;
    const f16* qp = qf + ((size_t)bh * kNp + row) * 64;
    aQ0 = *(const f16x8*)(qp + quad * 8);
    aQ1 = *(const f16x8*)(qp + 32 + quad * 8);
    const f16* ep = qe + ((size_t)bh * kNp + row) * 64;
    aQE0 = *(const f16x8*)(ep + quad * 8);
    aQE1 = *(const f16x8*)(ep + 32 + quad * 8);
  }
  // ones-column B-frag for the l-accumulating 5th PV tile
  f16x8 bOnes;
#pragma unroll
  for (int i = 0; i < 8; ++i) bOnes[i] = (frow == 0) ? (f16)1.f : (f16)0.f;

  f32x4 Oc[5];
#pragma unroll
  for (int t = 0; t < 5; ++t) Oc[t] = vzero;

  const f16* kba = kfrag + (size_t)bh * 13 * 8192;
  const f16* vba = vswz + (size_t)bh * 13 * 8192;
  f16* sPw = (f16*)(pool + wv * 4352);   // per-wave P: [16][136] f16, aliases sKa/sKb

  for (int kt = 0; kt < 13; ++kt) {
    __syncthreads();  // A: prior iter's sP/sV reads done before restaging
    {
      const f16* kfa = kba + (size_t)kt * 8192;
      const f16* koa = konefrag + (size_t)kt * 8192;
      const f16* vfa = vba + (size_t)kt * 8192;
#pragma unroll
      for (int i = 0; i < 4; ++i) {
        int u = (i * 256 + tid) * 8;
        *(u32x4*)&sKa[u] = *(const u32x4*)(kfa + u);
      }
#pragma unroll
      for (int i = 0; i < 4; ++i) {
        int u = (i * 256 + tid) * 8;
        *(u32x4*)&sKb[u] = *(const u32x4*)(koa + u);
      }
#pragma unroll
      for (int i = 0; i < 4; ++i) {
        int u = (i * 256 + tid) * 8;
        *(u32x4*)&sV[u] = *(const u32x4*)(vfa + u);
      }
    }
    __syncthreads();  // B: staging visible

    // QK^T + all biases + mask: 128 dims = 4 MFMA steps per key-group
    f32x4 Sc[8];
#pragma unroll
    for (int nt = 0; nt < 8; ++nt) {
      const f16* ka = &sKa[nt * 1024 + lane * 8];
      const f16* kb = &sKb[nt * 1024 + lane * 8];
      f32x4 s = MFMA16(aQ0, *(const f16x8*)(ka), vzero);
      s = MFMA16(aQ1, *(const f16x8*)(ka + 512), s);
      s = MFMA16(aQE0, *(const f16x8*)(kb), s);
      Sc[nt] = MFMA16(aQE1, *(const f16x8*)(kb + 512), s);
    }
    // P = exp2(Sc): no max, no rescale, no cross-lane
#pragma unroll
    for (int nt = 0; nt < 8; ++nt)
#pragma unroll
      for (int r = 0; r < 4; ++r)
        Sc[nt][r] = fast_exp2(Sc[nt][r]);
    // V fragments (sV not clobbered by P; load before the barrier)
    f16x8 bV[4][4];
#pragma unroll
    for (int td = 0; td < 4; ++td)
#pragma unroll
      for (int kc = 0; kc < 4; ++kc)
        bV[td][kc] = *(const f16x8*)&sV[(td * 4 + kc) * 512 + lane * 8];
    __syncthreads();  // C: all QK-phase sKa/sKb reads done; safe to clobber with P

    // P: C-layout -> per-wave LDS region -> A-layout
#pragma unroll
    for (int nt = 0; nt < 8; ++nt)
#pragma unroll
      for (int r = 0; r < 4; ++r)
        sPw[(quad * 4 + r) * 136 + nt * 16 + frow] = (f16)Sc[nt][r];
    // PV: O[16 x 64] += P @ V; Oc[4] accumulates row-sums l via bOnes
#pragma unroll
    for (int kc = 0; kc < 4; ++kc) {
      f16x8 aP = *(const f16x8*)&sPw[frow * 136 + kc * 32 + quad * 8];
#pragma unroll
      for (int td = 0; td < 4; ++td)
        Oc[td] = MFMA16(aP, bV[td][kc], Oc[td]);
      Oc[4] = MFMA16(aP, bOnes, Oc[4]);
    }
  }
  // epilogue: broadcast l from frow==0 lanes, normalize, store
  float lr[4];
#pragma unroll
  for (int r = 0; r < 4; ++r)
    lr[r] = 1.f / __shfl(Oc[4][r], lane & 48, 64);
#pragma unroll
  for (int td = 0; td < 4; ++td)
#pragma unroll
    for (int r = 0; r < 4; ++r) {
      int row = q0 + wv * 16 + quad * 4 + r;
      if (row < kN) {
        float val = Oc[td][r] * lr[r];
        Of[((size_t)(b * kN + row)) * 768 + hh * 64 + td * 16 + frow] = (f16)val;
      }
    }
}

// ---------------- proj GEMM: out[3136,768] = O[3136,768] @ Wp[768,768]^T + bias --
__global__ __launch_bounds__(256) void arp_gemm_proj(
    const f16* __restrict__ A, const float* __restrict__ W,
    const float* __restrict__ bias, float* __restrict__ out) {
  __shared__ f16 sA[128 * 40];
  __shared__ f16 sB[128 * 40];
  const int tid = threadIdx.x, lane = tid & 63, wv = tid >> 6;
  const int m0 = blockIdx.y * 128, n0 = blockIdx.x * 128;
  const int wm = (wv & 1) * 64, wn = (wv >> 1) * 64;
  const int frow = lane & 15, fcol = (lane >> 4) * 8;
  const f32x4 vzero = {0.f, 0.f, 0.f, 0.f};
  f32x4 acc[4][4];
  for (int i = 0; i < 4; ++i)
    for (int j = 0; j < 4; ++j) acc[i][j] = vzero;

  for (int kt = 0; kt < 24; ++kt) {
#pragma unroll
    for (int i = 0; i < 2; ++i) {
      int idx = i * 256 + tid;
      int r = idx >> 2, c8 = (idx & 3) * 8;
      u32x4 v = *(const u32x4*)(A + (size_t)(m0 + r) * 768 + kt * 32 + c8);
      *(u32x4*)&sA[r * 40 + c8] = v;
    }
#pragma unroll
    for (int i = 0; i < 4; ++i) {
      int idx = i * 256 + tid;
      int r = idx >> 3, c4 = (idx & 7) * 4;
      float4 v = *(const float4*)(W + (size_t)(n0 + r) * 768 + kt * 32 + c4);
      *(f16x4*)&sB[r * 40 + c4] = pack4(v);
    }
    __syncthreads();
    f16x8 af[4], bf[4];
#pragma unroll
    for (int t = 0; t < 4; ++t) {
      af[t] = *(const f16x8*)&sA[(wm + t * 16 + frow) * 40 + fcol];
      bf[t] = *(const f16x8*)&sB[(wn + t * 16 + frow) * 40 + fcol];
    }
#pragma unroll
    for (int mt = 0; mt < 4; ++mt)
#pragma unroll
      for (int nt = 0; nt < 4; ++nt)
        acc[mt][nt] = MFMA16(af[mt], bf[nt], acc[mt][nt]);
    __syncthreads();
  }
#pragma unroll
  for (int mt = 0; mt < 4; ++mt) {
    int rbase = m0 + wm + mt * 16 + (lane >> 4) * 4;
#pragma unroll
    for (int nt = 0; nt < 4; ++nt) {
      int col = n0 + wn + nt * 16 + frow;
      float bv = bias[col];
#pragma unroll
      for (int rg = 0; rg < 4; ++rg) {
        int m = rbase + rg;
        if (m < kM) out[(size_t)m * 768 + col] = acc[mt][nt][rg] + bv;
      }
    }
  }
}

extern "C" void kernel_launch(void* const* d_in, const int* in_sizes, int n_in,
                              void* d_out, int out_size, void* d_ws, size_t ws_size,
                              hipStream_t stream) {
  if (ws_size < WS_TOTAL) return;
  const float* x      = (const float*)d_in[0];
  const float* qkv_w  = (const float*)d_in[1];
  const float* proj_w = (const float*)d_in[2];
  const float* proj_b = (const float*)d_in[3];
  const float* rph    = (const float*)d_in[4];
  const float* rpw    = (const float*)d_in[5];
  const float* rpt    = (const float*)d_in[6];
  char* ws = (char*)d_ws;
  f16* qf       = (f16*)(ws + OFF_Q);
  f16* qe       = (f16*)(ws + OFF_QE);
  f16* kfrag    = (f16*)(ws + OFF_KF);
  f16* konefrag = (f16*)(ws + OFF_KONE);
  f16* vswz     = (f16*)(ws + OFF_VSWZ);
  f16* Of       = (f16*)(ws + OFF_O);

  int koneTot = 13 * 8 * 2 * 64 * 8;
  arp_konefrag<<<(koneTot + 255) / 256, 256, 0, stream>>>(konefrag);
  arp_gemm_qkv<<<dim3(18, 25), 256, 0, stream>>>(x, qkv_w, qf, kfrag, vswz);
  int qeTot = 24 * kN * 37;
  arp_qext<<<(qeTot + 255) / 256, 256, 0, stream>>>(qf, rph, rpw, rpt, qe);
  arp_attn<<<dim3(25, 24), 256, 0, stream>>>(qf, qe, kfrag, konefrag, vswz, Of);
  arp_gemm_proj<<<dim3(6, 25), 256, 0, stream>>>(Of, proj_w, proj_b, (float*)d_out);
}

// Round 8
// 246.260 us; speedup vs baseline: 1.2637x; 1.0360x over previous
//
#include <hip/hip_runtime.h>

using f16   = _Float16;
using f16x4 = __attribute__((ext_vector_type(4))) _Float16;
using f16x8 = __attribute__((ext_vector_type(8))) _Float16;
using f32x4 = __attribute__((ext_vector_type(4))) float;
using u32x4 = __attribute__((ext_vector_type(4))) unsigned int;
using fp16x2_raw = __fp16 __attribute__((ext_vector_type(2)));

#define MFMA16(a, b, c) __builtin_amdgcn_mfma_f32_16x16x32_f16((a), (b), (c), 0, 0, 0)

namespace {
constexpr int kT = 8, kWd = 14, kS = 196;
constexpr int kN = 1568;      // T*S (sequence length per batch)
constexpr int kM = 3136;      // B*N (GEMM rows)
constexpr int kHeads = 12;
constexpr int kNp = 1664;     // padded N (13*128)
constexpr float kLog2e = 1.4426950408889634f;
// workspace byte offsets (all 256-aligned); total 25378816 <= proven 26.9 MB budget
constexpr size_t OFF_WH   = 0;            // Wh   [2304][768] f16 (qkv_w converted)
constexpr size_t OFF_WP   = 3538944;      // Wp   [768][768]  f16 (proj_w converted)
constexpr size_t OFF_Q    = 4718592;      // qf   [24][Np][64] f16 (q*log2e); REUSED as O (in-place)
constexpr size_t OFF_QE   = 9830400;      // qe   [24][Np][64] f16 (rel dots*log2e; [36]=-30000)
constexpr size_t OFF_KF   = 14942208;     // kfrag[24][13][8][2][64][8] f16
constexpr size_t OFF_KONE = 20054016;     // konefrag [13][8][2][64][8] f16
constexpr size_t OFF_VSWZ = 20267008;     // vswz [24][13][4][4][64][8] f16
constexpr size_t WS_TOTAL = 25378816;

__device__ inline f16x4 pack4(float4 v) {
  union { fp16x2_raw h2[2]; f16x4 f4; } u;
  u.h2[0] = __builtin_amdgcn_cvt_pkrtz(v.x, v.y);
  u.h2[1] = __builtin_amdgcn_cvt_pkrtz(v.z, v.w);
  return u.f4;
}

__device__ inline float fast_exp2(float x) {
#if __has_builtin(__builtin_amdgcn_exp2f)
  return __builtin_amdgcn_exp2f(x);
#else
  return __expf(x * 0.6931471805599453f);
#endif
}
}

// ---------------- fp32 -> f16 weight conversion (one pass) ----------------------
__global__ __launch_bounds__(256) void arp_cvt(
    const float* __restrict__ qkvw, const float* __restrict__ projw,
    f16* __restrict__ Wh, f16* __restrict__ Wp) {
  int gid = blockIdx.x * 256 + threadIdx.x;
  const int NQ = (2304 * 768) / 4;   // 442368
  const int NP = (768 * 768) / 4;    // 147456
  if (gid < NQ) {
    *(f16x4*)(Wh + (size_t)gid * 4) = pack4(*(const float4*)(qkvw + (size_t)gid * 4));
  } else if (gid < NQ + NP) {
    int g = gid - NQ;
    *(f16x4*)(Wp + (size_t)g * 4) = pack4(*(const float4*)(projw + (size_t)g * 4));
  }
}

// ---------------- QKV GEMM: 128x256 tiles, f16 W, register-prefetch pipeline ----
// q stored *log2e; k stored *0.125 in kfrag fragment order; v stored in vswz
// fragment order via sE transpose (two 128-col halves). Grid (9, 25).
__global__ __launch_bounds__(256, 1) void arp_gemm_qkv(
    const float* __restrict__ X, const f16* __restrict__ Wh,
    f16* __restrict__ qf, f16* __restrict__ kfrag, f16* __restrict__ vswz) {
  __shared__ char smem[34816];        // loop: sA 10240 + sB 20480; epilogue: sE 34816
  f16* sA = (f16*)smem;               // [128][40] f16
  f16* sB = (f16*)(smem + 10240);     // [256][40] f16
  f16* sE = (f16*)smem;               // [128][136] f16 (aliases sA/sB)
  const int tid = threadIdx.x, lane = tid & 63, wv = tid >> 6;
  const int m0 = blockIdx.y * 128, n0 = blockIdx.x * 256;
  const int wm = (wv & 1) * 64, wn2 = (wv >> 1) * 128;
  const int frow = lane & 15, quad = lane >> 4, fcol = quad * 8;
  const f32x4 vzero = {0.f, 0.f, 0.f, 0.f};
  f32x4 acc[4][8];
#pragma unroll
  for (int i = 0; i < 4; ++i)
#pragma unroll
    for (int j = 0; j < 8; ++j) acc[i][j] = vzero;

  float4 pA[4];
  u32x4 pB[4];
  // prologue: prefetch kt=0
#pragma unroll
  for (int i = 0; i < 4; ++i) {
    int idx = i * 256 + tid;
    int r = idx >> 3, c4 = (idx & 7) * 4;
    int gm = m0 + r;
    float4 z = {0.f, 0.f, 0.f, 0.f};
    pA[i] = (gm < kM) ? *(const float4*)(X + (size_t)gm * 768 + c4) : z;
  }
#pragma unroll
  for (int i = 0; i < 4; ++i) {
    int idx = i * 256 + tid;
    int r = idx >> 2, c8 = (idx & 3) * 8;
    pB[i] = *(const u32x4*)(Wh + (size_t)(n0 + r) * 768 + c8);
  }

  for (int kt = 0; kt < 24; ++kt) {
    // commit prefetched tile to LDS
#pragma unroll
    for (int i = 0; i < 4; ++i) {
      int idx = i * 256 + tid;
      int r = idx >> 3, c4 = (idx & 7) * 4;
      *(f16x4*)&sA[r * 40 + c4] = pack4(pA[i]);
    }
#pragma unroll
    for (int i = 0; i < 4; ++i) {
      int idx = i * 256 + tid;
      int r = idx >> 2, c8 = (idx & 3) * 8;
      *(u32x4*)&sB[r * 40 + c8] = pB[i];
    }
    __syncthreads();
    // issue next tile's loads (overlap with MFMA below)
    if (kt < 23) {
#pragma unroll
      for (int i = 0; i < 4; ++i) {
        int idx = i * 256 + tid;
        int r = idx >> 3, c4 = (idx & 7) * 4;
        int gm = m0 + r;
        float4 z = {0.f, 0.f, 0.f, 0.f};
        pA[i] = (gm < kM) ? *(const float4*)(X + (size_t)gm * 768 + (kt + 1) * 32 + c4) : z;
      }
#pragma unroll
      for (int i = 0; i < 4; ++i) {
        int idx = i * 256 + tid;
        int r = idx >> 2, c8 = (idx & 3) * 8;
        pB[i] = *(const u32x4*)(Wh + (size_t)(n0 + r) * 768 + (kt + 1) * 32 + c8);
      }
    }
    f16x8 af[4], bf[8];
#pragma unroll
    for (int t = 0; t < 4; ++t)
      af[t] = *(const f16x8*)&sA[(wm + t * 16 + frow) * 40 + fcol];
#pragma unroll
    for (int u = 0; u < 8; ++u)
      bf[u] = *(const f16x8*)&sB[(wn2 + u * 16 + frow) * 40 + fcol];
#pragma unroll
    for (int mt = 0; mt < 4; ++mt)
#pragma unroll
      for (int nt = 0; nt < 8; ++nt)
        acc[mt][nt] = MFMA16(af[mt], bf[nt], acc[mt][nt]);
    __syncthreads();
  }

  const int which = n0 / 768;   // 0=q, 1=k, 2=v (256 | 768)
  if (which == 2) {
    // ---- v: transpose via sE in two 128-col halves, store vswz fragments ----
#pragma unroll
    for (int h = 0; h < 2; ++h) {
      __syncthreads();
      if ((wv >> 1) == h) {
#pragma unroll
        for (int mt = 0; mt < 4; ++mt)
#pragma unroll
          for (int nt = 0; nt < 8; ++nt) {
            int cl = nt * 16 + frow;            // 0..127 within half
#pragma unroll
            for (int rg = 0; rg < 4; ++rg) {
              int rl = wm + mt * 16 + quad * 4 + rg;
              sE[cl * 136 + rl] = (f16)acc[mt][nt][rg];
            }
          }
      }
      __syncthreads();
      int cl = tid >> 1;                 // 0..127
      int rb = (tid & 1) * 64;           // row-block 0/64
      int rem = n0 + h * 128 + cl - 1536;
      int hh = rem >> 6, d = rem & 63;
      int td = d >> 4, fr = d & 15;
#pragma unroll
      for (int j = 0; j < 8; ++j) {
        int ms = m0 + rb + j * 8;
        if (ms < kM) {
          int bb = (ms >= kN) ? 1 : 0;
          int ns = ms - bb * kN;
          int bh = bb * kHeads + hh;
          int kt2 = ns >> 7, kr = ns & 127;
          int kc = kr >> 5, qd = (kr >> 3) & 3;
          f16* dst = vswz + ((((size_t)(bh * 13 + kt2)) * 4 + td) * 4 + kc) * 512
                          + (qd * 16 + fr) * 8;
          *(u32x4*)dst = *(const u32x4*)&sE[cl * 136 + rb + j * 8];
        }
      }
    }
  } else {
    // ---- q/k: q direct (*log2e), k into kfrag fragment order (*0.125) ----
#pragma unroll
    for (int mt = 0; mt < 4; ++mt) {
      int rbase = m0 + wm + mt * 16 + quad * 4;
#pragma unroll
      for (int nt = 0; nt < 8; ++nt) {
        int col0 = n0 + wn2 + nt * 16;
        int rem = col0 - which * 768;
        int hh = rem >> 6;
        int d = (rem & 63) + frow;
        int s = d >> 5, qd2 = (d >> 3) & 3, j = d & 7;
#pragma unroll
        for (int rg = 0; rg < 4; ++rg) {
          int m = rbase + rg;
          if (m < kM) {
            int bb = (m >= kN) ? 1 : 0;
            int ns = m - bb * kN;
            int bh = bb * kHeads + hh;
            float av = acc[mt][nt][rg];
            if (which == 0) {
              av *= kLog2e;
              qf[((size_t)bh * kNp + ns) * 64 + d] = (f16)av;
            } else {
              av *= 0.125f;
              int kt2 = ns >> 7, nt2 = (ns >> 4) & 7, fr = ns & 15;
              kfrag[(((size_t)(bh * 13 + kt2) * 8 + nt2) * 2 + s) * 512
                    + (qd2 * 16 + fr) * 8 + j] = (f16)av;
            }
          }
        }
      }
    }
  }
}

// ---------------- one-hot ext fragments (bh-independent) ------------------------
__global__ __launch_bounds__(256) void arp_konefrag(f16* __restrict__ konefrag) {
  int gid = blockIdx.x * 256 + threadIdx.x;
  const int TOT = 13 * 8 * 2 * 64 * 8;
  if (gid >= TOT) return;
  int j = gid & 7;
  int lane = (gid >> 3) & 63;
  int s2 = (gid >> 9) & 1;
  int nt = (gid >> 10) & 7;
  int kt = gid >> 13;
  int fr = lane & 15, qd = lane >> 4;
  int key = kt * 128 + nt * 16 + fr;
  int c = s2 * 32 + qd * 8 + j;
  int t2 = key / kS; int rm = key - t2 * kS;
  int h2 = rm / kWd; int w2 = rm - h2 * kWd;
  if (t2 > kT - 1) t2 = kT - 1;
  float v = 0.f;
  if (c == h2) v = 1.f;
  else if (c == 14 + w2) v = 1.f;
  else if (c == 28 + t2) v = 1.f;
  else if (c == 36 && key >= kN) v = 1.f;
  konefrag[gid] = (f16)v;
}

// ---------------- Q extension: qe[bh][q][e] = (log2e-scaled) rel dots -----------
__global__ __launch_bounds__(256) void arp_qext(
    const f16* __restrict__ qf,
    const float* __restrict__ Rh, const float* __restrict__ Rw, const float* __restrict__ Rt,
    f16* __restrict__ qe) {
  int tid = blockIdx.x * 256 + threadIdx.x;
  const int TOT = 24 * kN * 37;
  if (tid >= TOT) return;
  int e = tid % 37;
  int rem = tid / 37;
  int q = rem % kN;
  int bh = rem / kN;
  f16* out = qe + ((size_t)bh * kNp + q) * 64;
  if (e == 36) { out[36] = (f16)(-30000.f); return; }
  int tq = q / kS, sr = q - tq * kS;
  int hq = sr / kWd, wq = sr - hq * kWd;
  const float* R;
  if (e < 14)      R = Rh + (hq - e + 13) * 64;
  else if (e < 28) R = Rw + (wq - (e - 14) + 13) * 64;
  else             R = Rt + (tq - (e - 28) + 7) * 64;
  const f16x8* qv = (const f16x8*)(qf + ((size_t)bh * kNp + q) * 64);
  const float4* R4 = (const float4*)R;
  float sum = 0.f;
#pragma unroll
  for (int i = 0; i < 8; ++i) {
    f16x8 qh = qv[i];
    float4 a = R4[i * 2], b = R4[i * 2 + 1];
    sum += (float)qh[0] * a.x + (float)qh[1] * a.y + (float)qh[2] * a.z + (float)qh[3] * a.w
         + (float)qh[4] * b.x + (float)qh[5] * b.y + (float)qh[6] * b.z + (float)qh[7] * b.w;
  }
  out[e] = (f16)sum;
}

// ---------------- flash attention: static-max log2 softmax; O in-place over qf --
// Each block reads qf rows [q0,q0+64) of its bh in the prologue and writes O to
// the SAME region in the epilogue (per-head layout) -> race-free in-place reuse.
__global__ __launch_bounds__(256, 3) void arp_attn(
    const f16* qf, const f16* __restrict__ qe,
    const f16* __restrict__ kfrag, const f16* __restrict__ konefrag,
    const f16* __restrict__ vswz, f16* qfO) {
  __shared__ char pool[49152];
  f16* sKa = (f16*)pool;             // 16384 B: K dims 0..63  [nt][s01][64][8]
  f16* sKb = (f16*)(pool + 16384);   // 16384 B: ext dims 64..127
  f16* sV  = (f16*)(pool + 32768);   // 16384 B: V frags [td][kc][64][8]

  const int tid = threadIdx.x, lane = tid & 63, wv = tid >> 6;
  const int q0 = blockIdx.x * 64;
  const int bh = blockIdx.y;
  const int frow = lane & 15, quad = lane >> 4;
  const f32x4 vzero = {0.f, 0.f, 0.f, 0.f};

  f16x8 aQ0, aQ1, aQE0, aQE1;
  {
    int row = q0 + wv * 16 + frow;
    const f16* qp = qf + ((size_t)bh * kNp + row) * 64;
    aQ0 = *(const f16x8*)(qp + quad * 8);
    aQ1 = *(const f16x8*)(qp + 32 + quad * 8);
    const f16* ep = qe + ((size_t)bh * kNp + row) * 64;
    aQE0 = *(const f16x8*)(ep + quad * 8);
    aQE1 = *(const f16x8*)(ep + 32 + quad * 8);
  }
  f16x8 bOnes;
#pragma unroll
  for (int i = 0; i < 8; ++i) bOnes[i] = (frow == 0) ? (f16)1.f : (f16)0.f;

  f32x4 Oc[5];
#pragma unroll
  for (int t = 0; t < 5; ++t) Oc[t] = vzero;

  const f16* kba = kfrag + (size_t)bh * 13 * 8192;
  const f16* vba = vswz + (size_t)bh * 13 * 8192;
  f16* sPw = (f16*)(pool + wv * 4352);   // per-wave P: [16][136] f16, aliases sKa/sKb

  for (int kt = 0; kt < 13; ++kt) {
    __syncthreads();  // A: prior iter's sP/sV reads done before restaging
    {
      const f16* kfa = kba + (size_t)kt * 8192;
      const f16* koa = konefrag + (size_t)kt * 8192;
      const f16* vfa = vba + (size_t)kt * 8192;
#pragma unroll
      for (int i = 0; i < 4; ++i) {
        int u = (i * 256 + tid) * 8;
        *(u32x4*)&sKa[u] = *(const u32x4*)(kfa + u);
      }
#pragma unroll
      for (int i = 0; i < 4; ++i) {
        int u = (i * 256 + tid) * 8;
        *(u32x4*)&sKb[u] = *(const u32x4*)(koa + u);
      }
#pragma unroll
      for (int i = 0; i < 4; ++i) {
        int u = (i * 256 + tid) * 8;
        *(u32x4*)&sV[u] = *(const u32x4*)(vfa + u);
      }
    }
    __syncthreads();  // B: staging visible

    f32x4 Sc[8];
#pragma unroll
    for (int nt = 0; nt < 8; ++nt) {
      const f16* ka = &sKa[nt * 1024 + lane * 8];
      const f16* kb = &sKb[nt * 1024 + lane * 8];
      f32x4 s = MFMA16(aQ0, *(const f16x8*)(ka), vzero);
      s = MFMA16(aQ1, *(const f16x8*)(ka + 512), s);
      s = MFMA16(aQE0, *(const f16x8*)(kb), s);
      Sc[nt] = MFMA16(aQE1, *(const f16x8*)(kb + 512), s);
    }
#pragma unroll
    for (int nt = 0; nt < 8; ++nt)
#pragma unroll
      for (int r = 0; r < 4; ++r)
        Sc[nt][r] = fast_exp2(Sc[nt][r]);
    f16x8 bV[4][4];
#pragma unroll
    for (int td = 0; td < 4; ++td)
#pragma unroll
      for (int kc = 0; kc < 4; ++kc)
        bV[td][kc] = *(const f16x8*)&sV[(td * 4 + kc) * 512 + lane * 8];
    __syncthreads();  // C: all QK-phase sKa/sKb reads done; safe to clobber with P

#pragma unroll
    for (int nt = 0; nt < 8; ++nt)
#pragma unroll
      for (int r = 0; r < 4; ++r)
        sPw[(quad * 4 + r) * 136 + nt * 16 + frow] = (f16)Sc[nt][r];
#pragma unroll
    for (int kc = 0; kc < 4; ++kc) {
      f16x8 aP = *(const f16x8*)&sPw[frow * 136 + kc * 32 + quad * 8];
#pragma unroll
      for (int td = 0; td < 4; ++td)
        Oc[td] = MFMA16(aP, bV[td][kc], Oc[td]);
      Oc[4] = MFMA16(aP, bOnes, Oc[4]);
    }
  }
  float lr[4];
#pragma unroll
  for (int r = 0; r < 4; ++r)
    lr[r] = 1.f / __shfl(Oc[4][r], lane & 48, 64);
#pragma unroll
  for (int td = 0; td < 4; ++td)
#pragma unroll
    for (int r = 0; r < 4; ++r) {
      int row = q0 + wv * 16 + quad * 4 + r;
      if (row < kN) {
        float val = Oc[td][r] * lr[r];
        qfO[((size_t)bh * kNp + row) * 64 + td * 16 + frow] = (f16)val;
      }
    }
}

// ---------------- proj GEMM: out = O @ Wp^T + bias; f16 operands + prefetch -----
// A read from per-head O layout (in-place over qf): col kt*32+c -> head kt>>1.
__global__ __launch_bounds__(256, 1) void arp_gemm_proj(
    const f16* A, const f16* __restrict__ Wp,
    const float* __restrict__ bias, float* __restrict__ out) {
  __shared__ f16 sA[128 * 40];
  __shared__ f16 sB[128 * 40];
  const int tid = threadIdx.x, lane = tid & 63, wv = tid >> 6;
  const int m0 = blockIdx.y * 128, n0 = blockIdx.x * 128;
  const int wm = (wv & 1) * 64, wn = (wv >> 1) * 64;
  const int frow = lane & 15, fcol = (lane >> 4) * 8;
  const f32x4 vzero = {0.f, 0.f, 0.f, 0.f};
  f32x4 acc[4][4];
#pragma unroll
  for (int i = 0; i < 4; ++i)
#pragma unroll
    for (int j = 0; j < 4; ++j) acc[i][j] = vzero;

  u32x4 pA[2], pB[2];
#pragma unroll
  for (int i = 0; i < 2; ++i) {
    int idx = i * 256 + tid;
    int r = idx >> 2, c8 = (idx & 3) * 8;
    int m = m0 + r;
    int bb = (m >= kN) ? 1 : 0;
    int ns = m - bb * kN;
    pA[i] = *(const u32x4*)(A + ((size_t)(bb * kHeads) * kNp + ns) * 64 + c8);
    pB[i] = *(const u32x4*)(Wp + (size_t)(n0 + r) * 768 + c8);
  }

  for (int kt = 0; kt < 24; ++kt) {
#pragma unroll
    for (int i = 0; i < 2; ++i) {
      int idx = i * 256 + tid;
      int r = idx >> 2, c8 = (idx & 3) * 8;
      *(u32x4*)&sA[r * 40 + c8] = pA[i];
      *(u32x4*)&sB[r * 40 + c8] = pB[i];
    }
    __syncthreads();
    if (kt < 23) {
      int k1 = kt + 1;
      int hd = k1 >> 1, dof = (k1 & 1) * 32;
#pragma unroll
      for (int i = 0; i < 2; ++i) {
        int idx = i * 256 + tid;
        int r = idx >> 2, c8 = (idx & 3) * 8;
        int m = m0 + r;
        int bb = (m >= kN) ? 1 : 0;
        int ns = m - bb * kN;
        pA[i] = *(const u32x4*)(A + ((size_t)(bb * kHeads + hd) * kNp + ns) * 64 + dof + c8);
        pB[i] = *(const u32x4*)(Wp + (size_t)(n0 + r) * 768 + k1 * 32 + c8);
      }
    }
    f16x8 af[4], bf[4];
#pragma unroll
    for (int t = 0; t < 4; ++t) {
      af[t] = *(const f16x8*)&sA[(wm + t * 16 + frow) * 40 + fcol];
      bf[t] = *(const f16x8*)&sB[(wn + t * 16 + frow) * 40 + fcol];
    }
#pragma unroll
    for (int mt = 0; mt < 4; ++mt)
#pragma unroll
      for (int nt = 0; nt < 4; ++nt)
        acc[mt][nt] = MFMA16(af[mt], bf[nt], acc[mt][nt]);
    __syncthreads();
  }
#pragma unroll
  for (int mt = 0; mt < 4; ++mt) {
    int rbase = m0 + wm + mt * 16 + (lane >> 4) * 4;
#pragma unroll
    for (int nt = 0; nt < 4; ++nt) {
      int col = n0 + wn + nt * 16 + frow;
      float bv = bias[col];
#pragma unroll
      for (int rg = 0; rg < 4; ++rg) {
        int m = rbase + rg;
        if (m < kM) out[(size_t)m * 768 + col] = acc[mt][nt][rg] + bv;
      }
    }
  }
}

extern "C" void kernel_launch(void* const* d_in, const int* in_sizes, int n_in,
                              void* d_out, int out_size, void* d_ws, size_t ws_size,
                              hipStream_t stream) {
  if (ws_size < WS_TOTAL) return;
  const float* x      = (const float*)d_in[0];
  const float* qkv_w  = (const float*)d_in[1];
  const float* proj_w = (const float*)d_in[2];
  const float* proj_b = (const float*)d_in[3];
  const float* rph    = (const float*)d_in[4];
  const float* rpw    = (const float*)d_in[5];
  const float* rpt    = (const float*)d_in[6];
  char* ws = (char*)d_ws;
  f16* Wh       = (f16*)(ws + OFF_WH);
  f16* Wp       = (f16*)(ws + OFF_WP);
  f16* qf       = (f16*)(ws + OFF_Q);     // becomes O after attn (in-place)
  f16* qe       = (f16*)(ws + OFF_QE);
  f16* kfrag    = (f16*)(ws + OFF_KF);
  f16* konefrag = (f16*)(ws + OFF_KONE);
  f16* vswz     = (f16*)(ws + OFF_VSWZ);

  arp_cvt<<<2304, 256, 0, stream>>>(qkv_w, proj_w, Wh, Wp);
  int koneTot = 13 * 8 * 2 * 64 * 8;
  arp_konefrag<<<(koneTot + 255) / 256, 256, 0, stream>>>(konefrag);
  arp_gemm_qkv<<<dim3(9, 25), 256, 0, stream>>>(x, Wh, qf, kfrag, vswz);
  int qeTot = 24 * kN * 37;
  arp_qext<<<(qeTot + 255) / 256, 256, 0, stream>>>(qf, rph, rpw, rpt, qe);
  arp_attn<<<dim3(25, 24), 256, 0, stream>>>(qf, qe, kfrag, konefrag, vswz, qf);
  arp_gemm_proj<<<dim3(6, 25), 256, 0, stream>>>(qf, Wp, proj_b, (float*)d_out);
}

// Round 9
// 231.896 us; speedup vs baseline: 1.3420x; 1.0619x over previous
//
#include <hip/hip_runtime.h>

using f16   = _Float16;
using f16x4 = __attribute__((ext_vector_type(4))) _Float16;
using f16x8 = __attribute__((ext_vector_type(8))) _Float16;
using f32x4 = __attribute__((ext_vector_type(4))) float;
using u32x4 = __attribute__((ext_vector_type(4))) unsigned int;
using fp16x2_raw = __fp16 __attribute__((ext_vector_type(2)));

#define MFMA16(a, b, c) __builtin_amdgcn_mfma_f32_16x16x32_f16((a), (b), (c), 0, 0, 0)

namespace {
constexpr int kT = 8, kWd = 14, kS = 196;
constexpr int kN = 1568;      // T*S (sequence length per batch)
constexpr int kM = 3136;      // B*N (GEMM rows)
constexpr int kHeads = 12;
constexpr int kNp = 1664;     // padded N (13*128)
constexpr float kLog2e = 1.4426950408889634f;
// workspace byte offsets (all 256-aligned); total 25378816 (proven budget)
constexpr size_t OFF_WH   = 0;            // Wh   [2304][768] f16
constexpr size_t OFF_WP   = 3538944;      // Wp   [768][768]  f16
constexpr size_t OFF_Q    = 4718592;      // qf   [24][Np][64] f16 (q*log2e); REUSED as O
constexpr size_t OFF_QE   = 9830400;      // qe   [24][Np][64] f16; ALSO Xh [3136][768] f16
                                          //   (Xh 4816896 B <= 5111808; dead before qext writes)
constexpr size_t OFF_KF   = 14942208;     // kfrag[24][13][8][2][64][8] f16
constexpr size_t OFF_KONE = 20054016;     // konefrag [13][8][2][64][8] f16
constexpr size_t OFF_VSWZ = 20267008;     // vswz [24][13][4][4][64][8] f16
constexpr size_t WS_TOTAL = 25378816;

__device__ inline f16x4 pack4(float4 v) {
  union { fp16x2_raw h2[2]; f16x4 f4; } u;
  u.h2[0] = __builtin_amdgcn_cvt_pkrtz(v.x, v.y);
  u.h2[1] = __builtin_amdgcn_cvt_pkrtz(v.z, v.w);
  return u.f4;
}

__device__ inline float fast_exp2(float x) {
#if __has_builtin(__builtin_amdgcn_exp2f)
  return __builtin_amdgcn_exp2f(x);
#else
  return __expf(x * 0.6931471805599453f);
#endif
}
}

// ---------------- fp32 -> f16 conversion: weights + X (one pass) ----------------
__global__ __launch_bounds__(256) void arp_cvt(
    const float* __restrict__ qkvw, const float* __restrict__ projw,
    const float* __restrict__ X,
    f16* __restrict__ Wh, f16* __restrict__ Wp, f16* __restrict__ Xh) {
  int gid = blockIdx.x * 256 + threadIdx.x;
  const int NQ = (2304 * 768) / 4;   // 442368
  const int NP = (768 * 768) / 4;    // 147456
  const int NX = (3136 * 768) / 4;   // 602112
  if (gid < NQ) {
    *(f16x4*)(Wh + (size_t)gid * 4) = pack4(*(const float4*)(qkvw + (size_t)gid * 4));
  } else if (gid < NQ + NP) {
    int g = gid - NQ;
    *(f16x4*)(Wp + (size_t)g * 4) = pack4(*(const float4*)(projw + (size_t)g * 4));
  } else if (gid < NQ + NP + NX) {
    int g = gid - NQ - NP;
    *(f16x4*)(Xh + (size_t)g * 4) = pack4(*(const float4*)(X + (size_t)g * 4));
  }
}

// ---------------- QKV GEMM: 128x128, all-f16 operands, register prefetch --------
// Grid (18, 25) = 450 blocks (~2/CU). q stored *log2e; k -> kfrag frag order;
// v -> vswz frag order via sE transpose. LDS 34816 B (sE aliases sA/sB).
__global__ __launch_bounds__(256, 2) void arp_gemm_qkv(
    const f16* __restrict__ Xh, const f16* __restrict__ Wh,
    f16* __restrict__ qf, f16* __restrict__ kfrag, f16* __restrict__ vswz) {
  __shared__ char smem[34816];
  f16* sA = (f16*)smem;               // [128][40]
  f16* sB = (f16*)(smem + 10240);     // [128][40]
  f16* sE = (f16*)smem;               // [128][136] (epilogue)
  const int tid = threadIdx.x, lane = tid & 63, wv = tid >> 6;
  const int m0 = blockIdx.y * 128, n0 = blockIdx.x * 128;
  const int wm = (wv & 1) * 64, wn = (wv >> 1) * 64;
  const int frow = lane & 15, quad = lane >> 4, fcol = quad * 8;
  const f32x4 vzero = {0.f, 0.f, 0.f, 0.f};
  f32x4 acc[4][4];
#pragma unroll
  for (int i = 0; i < 4; ++i)
#pragma unroll
    for (int j = 0; j < 4; ++j) acc[i][j] = vzero;

  u32x4 pA[2], pB[2];
  const u32x4 uz = {0, 0, 0, 0};
#pragma unroll
  for (int i = 0; i < 2; ++i) {
    int idx = i * 256 + tid;
    int r = idx >> 2, c8 = (idx & 3) * 8;
    int gm = m0 + r;
    pA[i] = (gm < kM) ? *(const u32x4*)(Xh + (size_t)gm * 768 + c8) : uz;
    pB[i] = *(const u32x4*)(Wh + (size_t)(n0 + r) * 768 + c8);
  }

  for (int kt = 0; kt < 24; ++kt) {
#pragma unroll
    for (int i = 0; i < 2; ++i) {
      int idx = i * 256 + tid;
      int r = idx >> 2, c8 = (idx & 3) * 8;
      *(u32x4*)&sA[r * 40 + c8] = pA[i];
      *(u32x4*)&sB[r * 40 + c8] = pB[i];
    }
    __syncthreads();
    if (kt < 23) {
      int ko = (kt + 1) * 32;
#pragma unroll
      for (int i = 0; i < 2; ++i) {
        int idx = i * 256 + tid;
        int r = idx >> 2, c8 = (idx & 3) * 8;
        int gm = m0 + r;
        pA[i] = (gm < kM) ? *(const u32x4*)(Xh + (size_t)gm * 768 + ko + c8) : uz;
        pB[i] = *(const u32x4*)(Wh + (size_t)(n0 + r) * 768 + ko + c8);
      }
    }
    f16x8 af[4], bf[4];
#pragma unroll
    for (int t = 0; t < 4; ++t) {
      af[t] = *(const f16x8*)&sA[(wm + t * 16 + frow) * 40 + fcol];
      bf[t] = *(const f16x8*)&sB[(wn + t * 16 + frow) * 40 + fcol];
    }
#pragma unroll
    for (int mt = 0; mt < 4; ++mt)
#pragma unroll
      for (int nt = 0; nt < 4; ++nt)
        acc[mt][nt] = MFMA16(af[mt], bf[nt], acc[mt][nt]);
    __syncthreads();
  }

  const int which = n0 / 768;   // 0=q, 1=k, 2=v
  if (which == 2) {
    // ---- v: transpose through sE, store vswz fragments (coalesced 16B) ----
#pragma unroll
    for (int mt = 0; mt < 4; ++mt)
#pragma unroll
      for (int nt = 0; nt < 4; ++nt) {
        int cl = wn + nt * 16 + frow;
#pragma unroll
        for (int rg = 0; rg < 4; ++rg) {
          int rl = wm + mt * 16 + quad * 4 + rg;
          sE[cl * 136 + rl] = (f16)acc[mt][nt][rg];
        }
      }
    __syncthreads();
    int cl = tid >> 1;
    int rb = (tid & 1) * 64;
    int rem = n0 + cl - 1536;
    int hh = rem >> 6, d = rem & 63;
    int td = d >> 4, fr = d & 15;
#pragma unroll
    for (int j = 0; j < 8; ++j) {
      int ms = m0 + rb + j * 8;
      if (ms < kM) {
        int bb = (ms >= kN) ? 1 : 0;
        int ns = ms - bb * kN;
        int bh = bb * kHeads + hh;
        int kt2 = ns >> 7, kr = ns & 127;
        int kc = kr >> 5, qd = (kr >> 3) & 3;
        f16* dst = vswz + ((((size_t)(bh * 13 + kt2)) * 4 + td) * 4 + kc) * 512
                        + (qd * 16 + fr) * 8;
        *(u32x4*)dst = *(const u32x4*)&sE[cl * 136 + rb + j * 8];
      }
    }
  } else {
    // ---- q/k: q direct (*log2e), k into kfrag fragment order (*0.125) ----
#pragma unroll
    for (int mt = 0; mt < 4; ++mt) {
      int rbase = m0 + wm + mt * 16 + quad * 4;
#pragma unroll
      for (int nt = 0; nt < 4; ++nt) {
        int col0 = n0 + wn + nt * 16;
        int rem = col0 - which * 768;
        int hh = rem >> 6;
        int d = (rem & 63) + frow;
        int s = d >> 5, qd2 = (d >> 3) & 3, j = d & 7;
#pragma unroll
        for (int rg = 0; rg < 4; ++rg) {
          int m = rbase + rg;
          if (m < kM) {
            int bb = (m >= kN) ? 1 : 0;
            int ns = m - bb * kN;
            int bh = bb * kHeads + hh;
            float av = acc[mt][nt][rg];
            if (which == 0) {
              av *= kLog2e;
              qf[((size_t)bh * kNp + ns) * 64 + d] = (f16)av;
            } else {
              av *= 0.125f;
              int kt2 = ns >> 7, nt2 = (ns >> 4) & 7, fr = ns & 15;
              kfrag[(((size_t)(bh * 13 + kt2) * 8 + nt2) * 2 + s) * 512
                    + (qd2 * 16 + fr) * 8 + j] = (f16)av;
            }
          }
        }
      }
    }
  }
}

// ---------------- one-hot ext fragments (bh-independent) ------------------------
__global__ __launch_bounds__(256) void arp_konefrag(f16* __restrict__ konefrag) {
  int gid = blockIdx.x * 256 + threadIdx.x;
  const int TOT = 13 * 8 * 2 * 64 * 8;
  if (gid >= TOT) return;
  int j = gid & 7;
  int lane = (gid >> 3) & 63;
  int s2 = (gid >> 9) & 1;
  int nt = (gid >> 10) & 7;
  int kt = gid >> 13;
  int fr = lane & 15, qd = lane >> 4;
  int key = kt * 128 + nt * 16 + fr;
  int c = s2 * 32 + qd * 8 + j;
  int t2 = key / kS; int rm = key - t2 * kS;
  int h2 = rm / kWd; int w2 = rm - h2 * kWd;
  if (t2 > kT - 1) t2 = kT - 1;
  float v = 0.f;
  if (c == h2) v = 1.f;
  else if (c == 14 + w2) v = 1.f;
  else if (c == 28 + t2) v = 1.f;
  else if (c == 36 && key >= kN) v = 1.f;
  konefrag[gid] = (f16)v;
}

// ---------------- Q extension: qe[bh][q][e] = (log2e-scaled) rel dots -----------
__global__ __launch_bounds__(256) void arp_qext(
    const f16* __restrict__ qf,
    const float* __restrict__ Rh, const float* __restrict__ Rw, const float* __restrict__ Rt,
    f16* __restrict__ qe) {
  int tid = blockIdx.x * 256 + threadIdx.x;
  const int TOT = 24 * kN * 37;
  if (tid >= TOT) return;
  int e = tid % 37;
  int rem = tid / 37;
  int q = rem % kN;
  int bh = rem / kN;
  f16* out = qe + ((size_t)bh * kNp + q) * 64;
  if (e == 36) { out[36] = (f16)(-30000.f); return; }
  int tq = q / kS, sr = q - tq * kS;
  int hq = sr / kWd, wq = sr - hq * kWd;
  const float* R;
  if (e < 14)      R = Rh + (hq - e + 13) * 64;
  else if (e < 28) R = Rw + (wq - (e - 14) + 13) * 64;
  else             R = Rt + (tq - (e - 28) + 7) * 64;
  const f16x8* qv = (const f16x8*)(qf + ((size_t)bh * kNp + q) * 64);
  const float4* R4 = (const float4*)R;
  float sum = 0.f;
#pragma unroll
  for (int i = 0; i < 8; ++i) {
    f16x8 qh = qv[i];
    float4 a = R4[i * 2], b = R4[i * 2 + 1];
    sum += (float)qh[0] * a.x + (float)qh[1] * a.y + (float)qh[2] * a.z + (float)qh[3] * a.w
         + (float)qh[4] * b.x + (float)qh[5] * b.y + (float)qh[6] * b.z + (float)qh[7] * b.w;
  }
  out[e] = (f16)sum;
}

// ---------------- flash attention: static-max log2 softmax; O in-place over qf --
__global__ __launch_bounds__(256, 3) void arp_attn(
    const f16* qf, const f16* __restrict__ qe,
    const f16* __restrict__ kfrag, const f16* __restrict__ konefrag,
    const f16* __restrict__ vswz, f16* qfO) {
  __shared__ char pool[49152];
  f16* sKa = (f16*)pool;             // 16384 B: K dims 0..63  [nt][s01][64][8]
  f16* sKb = (f16*)(pool + 16384);   // 16384 B: ext dims 64..127
  f16* sV  = (f16*)(pool + 32768);   // 16384 B: V frags [td][kc][64][8]

  const int tid = threadIdx.x, lane = tid & 63, wv = tid >> 6;
  const int q0 = blockIdx.x * 64;
  const int bh = blockIdx.y;
  const int frow = lane & 15, quad = lane >> 4;
  const f32x4 vzero = {0.f, 0.f, 0.f, 0.f};

  f16x8 aQ0, aQ1, aQE0, aQE1;
  {
    int row = q0 + wv * 16 + frow;
    const f16* qp = qf + ((size_t)bh * kNp + row) * 64;
    aQ0 = *(const f16x8*)(qp + quad * 8);
    aQ1 = *(const f16x8*)(qp + 32 + quad * 8);
    const f16* ep = qe + ((size_t)bh * kNp + row) * 64;
    aQE0 = *(const f16x8*)(ep + quad * 8);
    aQE1 = *(const f16x8*)(ep + 32 + quad * 8);
  }
  f16x8 bOnes;
#pragma unroll
  for (int i = 0; i < 8; ++i) bOnes[i] = (frow == 0) ? (f16)1.f : (f16)0.f;

  f32x4 Oc[5];
#pragma unroll
  for (int t = 0; t < 5; ++t) Oc[t] = vzero;

  const f16* kba = kfrag + (size_t)bh * 13 * 8192;
  const f16* vba = vswz + (size_t)bh * 13 * 8192;
  f16* sPw = (f16*)(pool + wv * 4352);   // per-wave P: [16][136] f16, aliases sKa/sKb

  for (int kt = 0; kt < 13; ++kt) {
    __syncthreads();  // A: prior iter's sP/sV reads done before restaging
    {
      const f16* kfa = kba + (size_t)kt * 8192;
      const f16* koa = konefrag + (size_t)kt * 8192;
      const f16* vfa = vba + (size_t)kt * 8192;
#pragma unroll
      for (int i = 0; i < 4; ++i) {
        int u = (i * 256 + tid) * 8;
        *(u32x4*)&sKa[u] = *(const u32x4*)(kfa + u);
      }
#pragma unroll
      for (int i = 0; i < 4; ++i) {
        int u = (i * 256 + tid) * 8;
        *(u32x4*)&sKb[u] = *(const u32x4*)(koa + u);
      }
#pragma unroll
      for (int i = 0; i < 4; ++i) {
        int u = (i * 256 + tid) * 8;
        *(u32x4*)&sV[u] = *(const u32x4*)(vfa + u);
      }
    }
    __syncthreads();  // B: staging visible

    f32x4 Sc[8];
#pragma unroll
    for (int nt = 0; nt < 8; ++nt) {
      const f16* ka = &sKa[nt * 1024 + lane * 8];
      const f16* kb = &sKb[nt * 1024 + lane * 8];
      f32x4 s = MFMA16(aQ0, *(const f16x8*)(ka), vzero);
      s = MFMA16(aQ1, *(const f16x8*)(ka + 512), s);
      s = MFMA16(aQE0, *(const f16x8*)(kb), s);
      Sc[nt] = MFMA16(aQE1, *(const f16x8*)(kb + 512), s);
    }
#pragma unroll
    for (int nt = 0; nt < 8; ++nt)
#pragma unroll
      for (int r = 0; r < 4; ++r)
        Sc[nt][r] = fast_exp2(Sc[nt][r]);
    f16x8 bV[4][4];
#pragma unroll
    for (int td = 0; td < 4; ++td)
#pragma unroll
      for (int kc = 0; kc < 4; ++kc)
        bV[td][kc] = *(const f16x8*)&sV[(td * 4 + kc) * 512 + lane * 8];
    __syncthreads();  // C: all QK-phase sKa/sKb reads done; safe to clobber with P

#pragma unroll
    for (int nt = 0; nt < 8; ++nt)
#pragma unroll
      for (int r = 0; r < 4; ++r)
        sPw[(quad * 4 + r) * 136 + nt * 16 + frow] = (f16)Sc[nt][r];
#pragma unroll
    for (int kc = 0; kc < 4; ++kc) {
      f16x8 aP = *(const f16x8*)&sPw[frow * 136 + kc * 32 + quad * 8];
#pragma unroll
      for (int td = 0; td < 4; ++td)
        Oc[td] = MFMA16(aP, bV[td][kc], Oc[td]);
      Oc[4] = MFMA16(aP, bOnes, Oc[4]);
    }
  }
  float lr[4];
#pragma unroll
  for (int r = 0; r < 4; ++r)
    lr[r] = 1.f / __shfl(Oc[4][r], lane & 48, 64);
#pragma unroll
  for (int td = 0; td < 4; ++td)
#pragma unroll
    for (int r = 0; r < 4; ++r) {
      int row = q0 + wv * 16 + quad * 4 + r;
      if (row < kN) {
        float val = Oc[td][r] * lr[r];
        qfO[((size_t)bh * kNp + row) * 64 + td * 16 + frow] = (f16)val;
      }
    }
}

// ---------------- proj GEMM: out = O @ Wp^T + bias; f16 operands + prefetch -----
__global__ __launch_bounds__(256, 1) void arp_gemm_proj(
    const f16* A, const f16* __restrict__ Wp,
    const float* __restrict__ bias, float* __restrict__ out) {
  __shared__ f16 sA[128 * 40];
  __shared__ f16 sB[128 * 40];
  const int tid = threadIdx.x, lane = tid & 63, wv = tid >> 6;
  const int m0 = blockIdx.y * 128, n0 = blockIdx.x * 128;
  const int wm = (wv & 1) * 64, wn = (wv >> 1) * 64;
  const int frow = lane & 15, fcol = (lane >> 4) * 8;
  const f32x4 vzero = {0.f, 0.f, 0.f, 0.f};
  f32x4 acc[4][4];
#pragma unroll
  for (int i = 0; i < 4; ++i)
#pragma unroll
    for (int j = 0; j < 4; ++j) acc[i][j] = vzero;

  u32x4 pA[2], pB[2];
#pragma unroll
  for (int i = 0; i < 2; ++i) {
    int idx = i * 256 + tid;
    int r = idx >> 2, c8 = (idx & 3) * 8;
    int m = m0 + r;
    int bb = (m >= kN) ? 1 : 0;
    int ns = m - bb * kN;
    pA[i] = *(const u32x4*)(A + ((size_t)(bb * kHeads) * kNp + ns) * 64 + c8);
    pB[i] = *(const u32x4*)(Wp + (size_t)(n0 + r) * 768 + c8);
  }

  for (int kt = 0; kt < 24; ++kt) {
#pragma unroll
    for (int i = 0; i < 2; ++i) {
      int idx = i * 256 + tid;
      int r = idx >> 2, c8 = (idx & 3) * 8;
      *(u32x4*)&sA[r * 40 + c8] = pA[i];
      *(u32x4*)&sB[r * 40 + c8] = pB[i];
    }
    __syncthreads();
    if (kt < 23) {
      int k1 = kt + 1;
      int hd = k1 >> 1, dof = (k1 & 1) * 32;
#pragma unroll
      for (int i = 0; i < 2; ++i) {
        int idx = i * 256 + tid;
        int r = idx >> 2, c8 = (idx & 3) * 8;
        int m = m0 + r;
        int bb = (m >= kN) ? 1 : 0;
        int ns = m - bb * kN;
        pA[i] = *(const u32x4*)(A + ((size_t)(bb * kHeads + hd) * kNp + ns) * 64 + dof + c8);
        pB[i] = *(const u32x4*)(Wp + (size_t)(n0 + r) * 768 + k1 * 32 + c8);
      }
    }
    f16x8 af[4], bf[4];
#pragma unroll
    for (int t = 0; t < 4; ++t) {
      af[t] = *(const f16x8*)&sA[(wm + t * 16 + frow) * 40 + fcol];
      bf[t] = *(const f16x8*)&sB[(wn + t * 16 + frow) * 40 + fcol];
    }
#pragma unroll
    for (int mt = 0; mt < 4; ++mt)
#pragma unroll
      for (int nt = 0; nt < 4; ++nt)
        acc[mt][nt] = MFMA16(af[mt], bf[nt], acc[mt][nt]);
    __syncthreads();
  }
#pragma unroll
  for (int mt = 0; mt < 4; ++mt) {
    int rbase = m0 + wm + mt * 16 + (lane >> 4) * 4;
#pragma unroll
    for (int nt = 0; nt < 4; ++nt) {
      int col = n0 + wn + nt * 16 + frow;
      float bv = bias[col];
#pragma unroll
      for (int rg = 0; rg < 4; ++rg) {
        int m = rbase + rg;
        if (m < kM) out[(size_t)m * 768 + col] = acc[mt][nt][rg] + bv;
      }
    }
  }
}

extern "C" void kernel_launch(void* const* d_in, const int* in_sizes, int n_in,
                              void* d_out, int out_size, void* d_ws, size_t ws_size,
                              hipStream_t stream) {
  if (ws_size < WS_TOTAL) return;
  const float* x      = (const float*)d_in[0];
  const float* qkv_w  = (const float*)d_in[1];
  const float* proj_w = (const float*)d_in[2];
  const float* proj_b = (const float*)d_in[3];
  const float* rph    = (const float*)d_in[4];
  const float* rpw    = (const float*)d_in[5];
  const float* rpt    = (const float*)d_in[6];
  char* ws = (char*)d_ws;
  f16* Wh       = (f16*)(ws + OFF_WH);
  f16* Wp       = (f16*)(ws + OFF_WP);
  f16* qf       = (f16*)(ws + OFF_Q);     // becomes O after attn (in-place)
  f16* qe       = (f16*)(ws + OFF_QE);    // Xh before qext overwrites it
  f16* Xh       = (f16*)(ws + OFF_QE);
  f16* kfrag    = (f16*)(ws + OFF_KF);
  f16* konefrag = (f16*)(ws + OFF_KONE);
  f16* vswz     = (f16*)(ws + OFF_VSWZ);

  const int cvtTot = (2304 * 768 + 768 * 768 + 3136 * 768) / 4;
  arp_cvt<<<(cvtTot + 255) / 256, 256, 0, stream>>>(qkv_w, proj_w, x, Wh, Wp, Xh);
  int koneTot = 13 * 8 * 2 * 64 * 8;
  arp_konefrag<<<(koneTot + 255) / 256, 256, 0, stream>>>(konefrag);
  arp_gemm_qkv<<<dim3(18, 25), 256, 0, stream>>>(Xh, Wh, qf, kfrag, vswz);
  int qeTot = 24 * kN * 37;
  arp_qext<<<(qeTot + 255) / 256, 256, 0, stream>>>(qf, rph, rpw, rpt, qe);
  arp_attn<<<dim3(25, 24), 256, 0, stream>>>(qf, qe, kfrag, konefrag, vswz, qf);
  arp_gemm_proj<<<dim3(6, 25), 256, 0, stream>>>(qf, Wp, proj_b, (float*)d_out);
}